// Round 1
// 510.318 us; speedup vs baseline: 1.1116x; 1.1116x over previous
//
#include <hip/hip_runtime.h>
#include <cmath>

// ---- problem constants ----
#define BATCH 16
#define HEADS 16
#define SEQ   512
#define DIM   64
#define QT    32          // q rows per block
#define NCHUNK 8          // key chunks of 64

#define LAMBDA_A 0.33f
#define LAMBDA_D 0.33f
#define LAMBDA_J 0.34f    // 1 - 0.33 - 0.33
#define NEG_BIG  1.0e12f

typedef float  floatx4 __attribute__((ext_vector_type(4)));
typedef short  shortx8 __attribute__((ext_vector_type(8)));
typedef short  shortx4 __attribute__((ext_vector_type(4)));

__device__ __forceinline__ unsigned short f2bf(float x){
  unsigned u = __builtin_bit_cast(unsigned, x);
  u += 0x7FFFu + ((u >> 16) & 1u);          // round-to-nearest-even
  return (unsigned short)(u >> 16);
}

// ---------------------------------------------------------------------------
// prep 1: W[b,q,k] = LAMBDA_D * p_dist + LAMBDA_J * adj_norm   (head-independent)
// one wave per (b,q) row; 2048 blocks x 256 threads
// ---------------------------------------------------------------------------
__global__ __launch_bounds__(256, 8) void prep_w_kernel(
    const float* __restrict__ adj, const float* __restrict__ dist,
    const float* __restrict__ mask, float* __restrict__ W)
{
  int tid  = threadIdx.x;
  int lane = tid & 63;
  int row  = blockIdx.x * 4 + (tid >> 6);     // 0 .. B*SEQ-1
  int b = row >> 9, q = row & (SEQ - 1);
  const float* arow = adj  + ((size_t)b * SEQ + q) * SEQ;
  const float* drow = dist + ((size_t)b * SEQ + q) * SEQ;
  const float* mrow = mask + (size_t)b * SEQ;

  floatx4 a[2], e[2];
  float asum = 0.f, dsum = 0.f;
#pragma unroll
  for (int i = 0; i < 2; i++){
    int c4 = (i * 64 + lane) * 4;
    a[i] = *(const floatx4*)(arow + c4);
    floatx4 d4 = *(const floatx4*)(drow + c4);
    floatx4 m4 = *(const floatx4*)(mrow + c4);
#pragma unroll
    for (int j = 0; j < 4; j++){
      asum += a[i][j];
      float ex = (m4[j] == 0.f) ? 0.f : __expf(-d4[j]);
      e[i][j] = ex;
      dsum += ex;
    }
  }
#pragma unroll
  for (int off = 1; off < 64; off <<= 1){
    asum += __shfl_xor(asum, off);
    dsum += __shfl_xor(dsum, off);
  }
  float ia = LAMBDA_J / (asum + 1e-6f);
  float id = LAMBDA_D / dsum;

  float* wrow = W + ((size_t)b * SEQ + q) * SEQ;
#pragma unroll
  for (int i = 0; i < 2; i++){
    int c4 = (i * 64 + lane) * 4;
    floatx4 w;
#pragma unroll
    for (int j = 0; j < 4; j++) w[j] = e[i][j] * id + a[i][j] * ia;
    *(floatx4*)(wrow + c4) = w;
  }
}

// ---------------------------------------------------------------------------
// prep 2: K -> bf16 (B,H,S,D), V -> bf16 transposed V^T (B,H,D,S)
// one block per (bh, 64-row chunk); 2048 blocks x 256 threads
// ---------------------------------------------------------------------------
__global__ __launch_bounds__(256, 8) void prep_kvt_kernel(
    const float* __restrict__ K, const float* __restrict__ V,
    unsigned short* __restrict__ Kb, unsigned short* __restrict__ VTb)
{
  int tid = threadIdx.x;
  int c   = blockIdx.x & 7;
  int bh  = blockIdx.x >> 3;
  const float* Kp = K + ((size_t)bh * SEQ + c * 64) * DIM;
  const float* Vp = V + ((size_t)bh * SEQ + c * 64) * DIM;
  unsigned short* Ko = Kb  + ((size_t)bh * SEQ + c * 64) * DIM;
  unsigned short* Vo = VTb + (size_t)bh * DIM * SEQ;

  __shared__ unsigned short sT[64 * 72];      // transposed bf16 tile [d][k]

  // K slice convert: 64x64 = 4096 elems, 16 per thread, coalesced
#pragma unroll
  for (int i = 0; i < 2; i++){
    int idx = (i * 256 + tid) * 8;
    floatx4 v0 = *(const floatx4*)(Kp + idx);
    floatx4 v1 = *(const floatx4*)(Kp + idx + 4);
    shortx8 hh;
#pragma unroll
    for (int j = 0; j < 4; j++){
      hh[j]     = (short)f2bf(v0[j]);
      hh[j + 4] = (short)f2bf(v1[j]);
    }
    *(shortx8*)(Ko + idx) = hh;
  }

  // V chunk transpose via LDS (padded rows -> no read conflicts)
#pragma unroll
  for (int i = 0; i < 4; i++){
    int idx = (i * 256 + tid) * 4;
    int k = idx >> 6, d = idx & 63;
    floatx4 v = *(const floatx4*)(Vp + idx);
#pragma unroll
    for (int j = 0; j < 4; j++) sT[(d + j) * 72 + k] = f2bf(v[j]);
  }
  __syncthreads();
#pragma unroll
  for (int i = 0; i < 2; i++){
    int idx = i * 256 + tid;
    int d = idx >> 3, k8 = idx & 7;
    shortx8 hh = *(const shortx8*)&sT[d * 72 + k8 * 8];
    *(shortx8*)(Vo + (size_t)d * SEQ + c * 64 + k8 * 8) = hh;
  }
}

// ---------------------------------------------------------------------------
// main fused kernel: per-block = one (b, h, q-tile of 32 rows)
// QK^T: A-fragments (Q) live in registers; B-fragments stream straight from
// L2-resident bf16 K -- zero barriers. PV: B-fragments stream from bf16 V^T;
// p_weighted goes through a double-buffered LDS tile (1 barrier / chunk).
// ---------------------------------------------------------------------------
__global__ __launch_bounds__(256, 4) void attn_kernel(
    const float* __restrict__ Q, const unsigned short* __restrict__ Kb,
    const unsigned short* __restrict__ VTb, const float* __restrict__ mask,
    const float* __restrict__ W, float* __restrict__ out, float* __restrict__ pattn)
{
  int bx  = blockIdx.x;
  int h   = bx & 15;
  int rest= bx >> 4;
  int qt  = rest & 15;
  int b   = rest >> 4;
  int bh  = b * HEADS + h;
  int q0  = qt * QT;

  int tid  = threadIdx.x;
  int wave = tid >> 6;
  int lane = tid & 63;
  int l15  = lane & 15;
  int quad = lane >> 4;
  int mtile = wave & 1;     // which 16-row half of the q tile
  int p     = wave >> 1;    // ntile parity

  __shared__ float sMask[SEQ];
  __shared__ unsigned short sPW[2][32 * 72];  // double-buffered p_weighted tile
  __shared__ float sRedM[2][32];
  __shared__ float sRedS[2][32];

  sMask[tid]       = mask[b * SEQ + tid];
  sMask[tid + 256] = mask[b * SEQ + tid + 256];

  // ---- Q fragments in registers (prescaled by 1/8), constant over all chunks
  const float* Qb = Q + ((size_t)bh * SEQ + q0 + mtile * 16 + l15) * DIM;
  shortx8 af[2];
#pragma unroll
  for (int ks = 0; ks < 2; ks++){
    const float* qp = Qb + ks * 32 + quad * 8;
    floatx4 v0 = *(const floatx4*)qp;
    floatx4 v1 = *(const floatx4*)(qp + 4);
#pragma unroll
    for (int j = 0; j < 4; j++){
      af[ks][j]     = (short)f2bf(v0[j] * 0.125f);
      af[ks][j + 4] = (short)f2bf(v1[j] * 0.125f);
    }
  }
  __syncthreads();            // sMask visible before softmax phase

  // ---- QK^T: 8 chunks, direct-global B-fragments, no barriers ----
  const unsigned short* Kw = Kb + (size_t)bh * SEQ * DIM
                               + (size_t)(p * 16 + l15) * DIM + quad * 8;
  floatx4 acc[16];
#pragma unroll
  for (int j = 0; j < 16; j++) acc[j] = (floatx4)0.f;
#pragma unroll
  for (int cc = 0; cc < NCHUNK; cc++){
    const unsigned short* Kc = Kw + cc * 64 * DIM;
#pragma unroll
    for (int ks = 0; ks < 2; ks++){
      shortx8 b0 = *(const shortx8*)(Kc + ks * 32);
      acc[2 * cc]     = __builtin_amdgcn_mfma_f32_16x16x32_bf16(af[ks], b0, acc[2 * cc], 0, 0, 0);
      shortx8 b1 = *(const shortx8*)(Kc + 32 * DIM + ks * 32);
      acc[2 * cc + 1] = __builtin_amdgcn_mfma_f32_16x16x32_bf16(af[ks], b1, acc[2 * cc + 1], 0, 0, 0);
    }
  }

  // ---- softmax (row = mtile*16 + quad*4 + r, col = (2j+p)*16 + l15) ----
  float vmax[4] = {-INFINITY, -INFINITY, -INFINITY, -INFINITY};
#pragma unroll
  for (int j = 0; j < 16; j++){
    int n = (2 * j + p) * 16 + l15;
    bool msk0 = (sMask[n] == 0.f);
#pragma unroll
    for (int r = 0; r < 4; r++){
      float s = msk0 ? -NEG_BIG : acc[j][r];
      acc[j][r] = s;
      vmax[r] = fmaxf(vmax[r], s);
    }
  }
#pragma unroll
  for (int r = 0; r < 4; r++){
#pragma unroll
    for (int off = 1; off < 16; off <<= 1)
      vmax[r] = fmaxf(vmax[r], __shfl_xor(vmax[r], off));
  }
  if (l15 == 0){
#pragma unroll
    for (int r = 0; r < 4; r++) sRedM[p][mtile * 16 + quad * 4 + r] = vmax[r];
  }
  __syncthreads();
  float mrow[4];
#pragma unroll
  for (int r = 0; r < 4; r++){
    int ridx = mtile * 16 + quad * 4 + r;
    mrow[r] = fmaxf(sRedM[0][ridx], sRedM[1][ridx]);
  }
  float vsum[4] = {0.f, 0.f, 0.f, 0.f};
#pragma unroll
  for (int j = 0; j < 16; j++){
#pragma unroll
    for (int r = 0; r < 4; r++){
      float e = __expf(acc[j][r] - mrow[r]);
      acc[j][r] = e;
      vsum[r] += e;
    }
  }
#pragma unroll
  for (int r = 0; r < 4; r++){
#pragma unroll
    for (int off = 1; off < 16; off <<= 1)
      vsum[r] += __shfl_xor(vsum[r], off);
  }
  if (l15 == 0){
#pragma unroll
    for (int r = 0; r < 4; r++) sRedS[p][mtile * 16 + quad * 4 + r] = vsum[r];
  }
  __syncthreads();
  float inv_l[4];
#pragma unroll
  for (int r = 0; r < 4; r++){
    int ridx = mtile * 16 + quad * 4 + r;
    inv_l[r] = 1.f / (sRedS[0][ridx] + sRedS[1][ridx]);
  }

  // ---- PV: p_weighted via double-buffered LDS, V^T fragments direct-global ----
  float* pA = pattn + ((size_t)bh * SEQ + q0) * SEQ;
  const float* Wq = W + ((size_t)b * SEQ + q0) * SEQ;
  const unsigned short* Vw = VTb + (size_t)bh * DIM * SEQ
                                 + (size_t)(p * 16 + l15) * SEQ + quad * 8;

  floatx4 acc2[2];
  acc2[0] = (floatx4)0.f;
  acc2[1] = (floatx4)0.f;

  // prefetch W for chunk 0
  float wreg[4][2];
#pragma unroll
  for (int r = 0; r < 4; r++){
    int rl = mtile * 16 + quad * 4 + r;
#pragma unroll
    for (int jj = 0; jj < 2; jj++){
      int nloc = (2 * jj + p) * 16 + l15;
      wreg[r][jj] = Wq[(size_t)rl * SEQ + nloc];
    }
  }

#pragma unroll
  for (int cc = 0; cc < NCHUNK; cc++){
    int buf = cc & 1;
    // V^T fragments for this chunk (independent of sPW -> issue early)
    shortx8 vt0[2], vt1[2];
#pragma unroll
    for (int ks = 0; ks < 2; ks++){
      vt0[ks] = *(const shortx8*)(Vw + cc * 64 + ks * 32);
      vt1[ks] = *(const shortx8*)(Vw + (size_t)32 * SEQ + cc * 64 + ks * 32);
    }
    // build p_weighted tile + store p_attn
#pragma unroll
    for (int r = 0; r < 4; r++){
      int rl = mtile * 16 + quad * 4 + r;
#pragma unroll
      for (int jj = 0; jj < 2; jj++){
        int nloc = (2 * jj + p) * 16 + l15;
        int n    = cc * 64 + nloc;
        float pa = acc[2 * cc + jj][r] * inv_l[r];
        __builtin_nontemporal_store(pa, &pA[(size_t)rl * SEQ + n]);
        float pw = LAMBDA_A * pa + wreg[r][jj];
        sPW[buf][rl * 72 + nloc] = f2bf(pw);
      }
    }
    // prefetch W for next chunk (hidden under barrier + MFMA)
    int cn = (cc + 1) & 7;
#pragma unroll
    for (int r = 0; r < 4; r++){
      int rl = mtile * 16 + quad * 4 + r;
#pragma unroll
      for (int jj = 0; jj < 2; jj++){
        int nloc = (2 * jj + p) * 16 + l15;
        wreg[r][jj] = Wq[(size_t)rl * SEQ + cn * 64 + nloc];
      }
    }
    __syncthreads();
#pragma unroll
    for (int ks = 0; ks < 2; ks++){
      shortx8 a2 = *(const shortx8*)&sPW[buf][(mtile * 16 + l15) * 72 + ks * 32 + quad * 8];
      acc2[0] = __builtin_amdgcn_mfma_f32_16x16x32_bf16(a2, vt0[ks], acc2[0], 0, 0, 0);
      acc2[1] = __builtin_amdgcn_mfma_f32_16x16x32_bf16(a2, vt1[ks], acc2[1], 0, 0, 0);
    }
  }

  // ---- epilogue: out (B,H,S,D) ----
  float* ob = out + ((size_t)bh * SEQ + q0) * DIM;
#pragma unroll
  for (int t = 0; t < 2; t++){
    int nt = p + 2 * t;
#pragma unroll
    for (int r = 0; r < 4; r++){
      int rl = mtile * 16 + quad * 4 + r;
      __builtin_nontemporal_store(acc2[t][r], &ob[(size_t)rl * DIM + nt * 16 + l15]);
    }
  }
}

extern "C" void kernel_launch(void* const* d_in, const int* in_sizes, int n_in,
                              void* d_out, int out_size, void* d_ws, size_t ws_size,
                              hipStream_t stream){
  const float* Q    = (const float*)d_in[0];
  const float* K    = (const float*)d_in[1];
  const float* V    = (const float*)d_in[2];
  const float* mask = (const float*)d_in[3];
  const float* adj  = (const float*)d_in[4];
  const float* dist = (const float*)d_in[5];
  float* out   = (float*)d_out;
  float* pattn = out + (size_t)BATCH * HEADS * SEQ * DIM;   // 8,388,608

  // workspace layout (48 MiB):
  //   [0,16M)   W     f32  (B,S,S)   head-independent weight term
  //   [16M,32M) Kb    bf16 (B,H,S,D)
  //   [32M,48M) VT    bf16 (B,H,D,S)
  float*          Wbuf = (float*)d_ws;
  unsigned short* Kb   = (unsigned short*)((char*)d_ws + (size_t)16 * 1024 * 1024);
  unsigned short* VTb  = (unsigned short*)((char*)d_ws + (size_t)32 * 1024 * 1024);

  prep_w_kernel  <<<BATCH * SEQ / 4,            256, 0, stream>>>(adj, dist, mask, Wbuf);
  prep_kvt_kernel<<<BATCH * HEADS * NCHUNK,     256, 0, stream>>>(K, V, Kb, VTb);
  attn_kernel    <<<BATCH * HEADS * (SEQ / QT), 256, 0, stream>>>(Q, Kb, VTb, mask, Wbuf,
                                                                  out, pattn);
}